// Round 16
// baseline (147.994 us; speedup 1.0000x reference)
//
#include <hip/hip_runtime.h>

typedef unsigned short u16;
typedef unsigned int u32;
typedef short v8s __attribute__((ext_vector_type(8)));
typedef float f32x4 __attribute__((ext_vector_type(4)));
typedef float f32x16 __attribute__((ext_vector_type(16)));

#define S_LEN 4096
#define DM 1024
#define HDIM 64
#define CEXP 0.18033688f /* 0.125 * log2(e), folded into Q at GEMM epilogue */

// ---- helpers ----------------------------------------------------------
__device__ __forceinline__ u16 f2bs(float f) {
  u32 u = __float_as_uint(f);
  u32 r = 0x7FFFu + ((u >> 16) & 1u);
  return (u16)((u + r) >> 16);
}

__device__ __forceinline__ float fexp2(float x) {
  float r;
  asm("v_exp_f32 %0, %1" : "=v"(r) : "v"(x));   // raw 2^x, args bounded
  return r;
}

__device__ __forceinline__ void gstage16(const void* g, void* lds_wave_base) {
  __builtin_amdgcn_global_load_lds(
      (const __attribute__((address_space(1))) u32*)g,
      (__attribute__((address_space(3))) u32*)lds_wave_base, 16, 0, 0);
}

__device__ __forceinline__ f32x16 vzero16() {
  f32x16 v;
#pragma unroll
  for (int r = 0; r < 16; ++r) v[r] = 0.f;
  return v;
}

// ---- fused prep: 4x weight transpose+cvt (64x64 tiles) + x fp32->bf16 --
// grid (16,16,5): z<4 -> wtrans w[z]; z==4 -> cvt (grid-strided, 8/thread)
__global__ __launch_bounds__(256) void k_prep(
    const float* __restrict__ x,
    const float* __restrict__ w0, const float* __restrict__ w1,
    const float* __restrict__ w2, const float* __restrict__ w3,
    u16* __restrict__ xb,
    u16* __restrict__ t0, u16* __restrict__ t1,
    u16* __restrict__ t2, u16* __restrict__ t3) {
  const int z = blockIdx.z;
  if (z < 4) {
    __shared__ float tile[64][65];
    const float* w; u16* wt;
    switch (z) {
      case 0: w = w0; wt = t0; break;
      case 1: w = w1; wt = t1; break;
      case 2: w = w2; wt = t2; break;
      default: w = w3; wt = t3; break;
    }
    const int r = threadIdx.x >> 4;          // 0..15
    const int c4 = (threadIdx.x & 15) * 4;   // 0..60
    const int k0 = blockIdx.x * 64, n0 = blockIdx.y * 64;
#pragma unroll
    for (int i = 0; i < 4; ++i) {
      const int row = r + i * 16;
      float4 v = *reinterpret_cast<const float4*>(w + (size_t)(k0 + row) * DM + n0 + c4);
      tile[row][c4] = v.x; tile[row][c4 + 1] = v.y;
      tile[row][c4 + 2] = v.z; tile[row][c4 + 3] = v.w;
    }
    __syncthreads();
#pragma unroll
    for (int i = 0; i < 4; ++i) {
      const int row = r + i * 16;            // output n-row
      u16 o4[4] = {f2bs(tile[c4][row]), f2bs(tile[c4 + 1][row]),
                   f2bs(tile[c4 + 2][row]), f2bs(tile[c4 + 3][row])};
      *reinterpret_cast<uint2*>(wt + (size_t)(n0 + row) * DM + k0 + c4) =
          *reinterpret_cast<const uint2*>(o4);
    }
  } else {
    // cvt: 256 blocks x 256 threads x 8 uint4 = 524288 uint4 (4M floats)
    const int bid = blockIdx.y * 16 + blockIdx.x;
#pragma unroll
    for (int j = 0; j < 8; ++j) {
      const int ci = j * 65536 + bid * 256 + threadIdx.x;
      const float4* p = reinterpret_cast<const float4*>(x) + (size_t)ci * 2;
      float4 a = p[0], b = p[1];
      u16 t[8] = {f2bs(a.x), f2bs(a.y), f2bs(a.z), f2bs(a.w),
                  f2bs(b.x), f2bs(b.y), f2bs(b.z), f2bs(b.w)};
      reinterpret_cast<uint4*>(xb)[ci] = *reinterpret_cast<const uint4*>(t);
    }
  }
}

// ---- GEMM core (128x128, BK=64): C = A[M,K] @ Bt[N,K]^T + bias ---------
// Staging: 1024 slots/operand of 16B; slot s -> row=s>>3, chunk=(s&7)^(row&7)
template <int MODE>
__device__ __forceinline__ void gemm_core(
    u16* __restrict__ As, u16* __restrict__ Bs,
    const u16* __restrict__ A, const u16* __restrict__ Bt,
    const float* __restrict__ bias, void* __restrict__ Cout, float oscale) {
  constexpr int K = DM;
  const int tid = threadIdx.x;
  const int lane = tid & 63, wave = tid >> 6;
  const int wm = wave >> 1, wn = wave & 1;
  const int l15 = lane & 15, l4 = lane >> 4;
  const int bm0 = blockIdx.x * 128, bn0 = blockIdx.y * 128;

  f32x4 acc[4][4];
#pragma unroll
  for (int m = 0; m < 4; ++m)
#pragma unroll
    for (int n = 0; n < 4; ++n) acc[m][n] = 0.f;

  int ra[4], ca[4];
#pragma unroll
  for (int i = 0; i < 4; ++i) {
    const int s = i * 256 + tid;
    ra[i] = s >> 3;
    ca[i] = ((s & 7) ^ (ra[i] & 7)) * 8;
  }
  const u16* Ab = A + (size_t)bm0 * K;
  const u16* Bb = Bt + (size_t)bn0 * K;

  for (int k0 = 0; k0 < K; k0 += 64) {
#pragma unroll
    for (int i = 0; i < 4; ++i) {
      gstage16(Ab + (size_t)ra[i] * K + k0 + ca[i], As + (size_t)(i * 256 + wave * 64) * 8);
      gstage16(Bb + (size_t)ra[i] * K + k0 + ca[i], Bs + (size_t)(i * 256 + wave * 64) * 8);
    }
    __syncthreads();
#pragma unroll
    for (int s = 0; s < 2; ++s) {
      v8s af[4], bfr[4];
#pragma unroll
      for (int m = 0; m < 4; ++m) {
        const int rowa = wm * 64 + m * 16 + l15;
        af[m] = *reinterpret_cast<const v8s*>(
            As + (size_t)(rowa * 8 + ((s * 4 + l4) ^ (rowa & 7))) * 8);
        const int rowb = wn * 64 + m * 16 + l15;
        bfr[m] = *reinterpret_cast<const v8s*>(
            Bs + (size_t)(rowb * 8 + ((s * 4 + l4) ^ (rowb & 7))) * 8);
      }
#pragma unroll
      for (int m = 0; m < 4; ++m)
#pragma unroll
        for (int n = 0; n < 4; ++n)
          acc[m][n] = __builtin_amdgcn_mfma_f32_16x16x32_bf16(af[m], bfr[n], acc[m][n], 0, 0, 0);
    }
    __syncthreads();
  }

#pragma unroll
  for (int m = 0; m < 4; ++m) {
    const int gs0 = bm0 + wm * 64 + m * 16 + l4 * 4;
#pragma unroll
    for (int n = 0; n < 4; ++n) {
      const int gn = bn0 + wn * 64 + n * 16 + l15;
      const float bv = bias[gn];
      if (MODE == 0) {
        u16* O = (u16*)Cout;
        const size_t base = (size_t)(gn >> 6) * (S_LEN * HDIM) + (size_t)(gn & 63);
#pragma unroll
        for (int r = 0; r < 4; ++r)
          O[base + (size_t)(gs0 + r) * HDIM] = f2bs((acc[m][n][r] + bv) * oscale);
      } else {
        u16* O = (u16*)Cout;
        u16 p4[4];
#pragma unroll
        for (int r = 0; r < 4; ++r) p4[r] = f2bs(acc[m][n][r] + bv);
        *reinterpret_cast<uint2*>(O + (size_t)(gn >> 6) * (HDIM * S_LEN) +
                                  (size_t)(gn & 63) * S_LEN + gs0) =
            *reinterpret_cast<const uint2*>(p4);
      }
    }
  }
}

__global__ __launch_bounds__(256) void k_gemm_qkv(
    const u16* __restrict__ A,
    const u16* __restrict__ wq, const u16* __restrict__ wk, const u16* __restrict__ wv,
    const float* __restrict__ bq, const float* __restrict__ bk, const float* __restrict__ bv,
    u16* __restrict__ Qo, u16* __restrict__ Ko, u16* __restrict__ Vo) {
  __shared__ __attribute__((aligned(16))) u16 As[128 * 64];
  __shared__ __attribute__((aligned(16))) u16 Bs[128 * 64];
  const int z = blockIdx.z;
  if (z == 0)      gemm_core<0>(As, Bs, A, wq, bq, Qo, CEXP);
  else if (z == 1) gemm_core<0>(As, Bs, A, wk, bk, Ko, 1.f);
  else             gemm_core<1>(As, Bs, A, wv, bv, Vo, 1.f);
}

// ---- output GEMM, 128x64 tiles, BK=64: grid (32,16) = 512 blocks -------
__global__ __launch_bounds__(256) void k_gemm_o(
    const u16* __restrict__ A, const u16* __restrict__ wo,
    const float* __restrict__ bo, float* __restrict__ out) {
  __shared__ __attribute__((aligned(16))) u16 As[128 * 64];
  __shared__ __attribute__((aligned(16))) u16 Bs[64 * 64];
  constexpr int K = DM, N = DM;
  const int tid = threadIdx.x;
  const int lane = tid & 63, wave = tid >> 6;
  const int wm = wave >> 1, wn = wave & 1;
  const int l15 = lane & 15, l4 = lane >> 4;
  const int bm0 = blockIdx.x * 128, bn0 = blockIdx.y * 64;

  f32x4 acc[4][2];
#pragma unroll
  for (int m = 0; m < 4; ++m)
#pragma unroll
    for (int n = 0; n < 2; ++n) acc[m][n] = 0.f;

  int ra[4], ca[4];
#pragma unroll
  for (int i = 0; i < 4; ++i) {
    const int s = i * 256 + tid;
    ra[i] = s >> 3;
    ca[i] = ((s & 7) ^ (ra[i] & 7)) * 8;
  }
  const u16* Ab = A + (size_t)bm0 * K;
  const u16* Bb = wo + (size_t)bn0 * K;

  for (int k0 = 0; k0 < K; k0 += 64) {
#pragma unroll
    for (int i = 0; i < 4; ++i)
      gstage16(Ab + (size_t)ra[i] * K + k0 + ca[i], As + (size_t)(i * 256 + wave * 64) * 8);
#pragma unroll
    for (int i = 0; i < 2; ++i)
      gstage16(Bb + (size_t)ra[i] * K + k0 + ca[i], Bs + (size_t)(i * 256 + wave * 64) * 8);
    __syncthreads();
#pragma unroll
    for (int s = 0; s < 2; ++s) {
      v8s af[4], bfr[2];
#pragma unroll
      for (int m = 0; m < 4; ++m) {
        const int rowa = wm * 64 + m * 16 + l15;
        af[m] = *reinterpret_cast<const v8s*>(
            As + (size_t)(rowa * 8 + ((s * 4 + l4) ^ (rowa & 7))) * 8);
      }
#pragma unroll
      for (int n = 0; n < 2; ++n) {
        const int rowb = wn * 32 + n * 16 + l15;
        bfr[n] = *reinterpret_cast<const v8s*>(
            Bs + (size_t)(rowb * 8 + ((s * 4 + l4) ^ (rowb & 7))) * 8);
      }
#pragma unroll
      for (int m = 0; m < 4; ++m)
#pragma unroll
        for (int n = 0; n < 2; ++n)
          acc[m][n] = __builtin_amdgcn_mfma_f32_16x16x32_bf16(af[m], bfr[n], acc[m][n], 0, 0, 0);
    }
    __syncthreads();
  }

#pragma unroll
  for (int m = 0; m < 4; ++m) {
    const int gs0 = bm0 + wm * 64 + m * 16 + l4 * 4;
#pragma unroll
    for (int n = 0; n < 2; ++n) {
      const int gn = bn0 + wn * 32 + n * 16 + l15;
      const float bv = bo[gn];
#pragma unroll
      for (int r = 0; r < 4; ++r)
        out[(size_t)(gs0 + r) * N + gn] = acc[m][n][r] + bv;
    }
  }
}

// ---- flash attention: Q,K [H][S][64] (Q pre-scaled by CEXP), Vt [H][64][S]
// -> Aout bf16 [S][DM]. (r12 structure — measured plateau of this topology:
// 4 waves x 32 q-rows, 32x32x16 MFMA, in-register softmax via cvt_pk+permlane,
// 4-buffer K/V ring with ONE barrier per TWO tiles, VALU denominator.)
__global__ __launch_bounds__(256, 2) void k_attn(
    const u16* __restrict__ Q, const u16* __restrict__ Kg,
    const u16* __restrict__ Vt, u16* __restrict__ Aout) {
  __shared__ __attribute__((aligned(16))) u16 Ks[4][64 * 64];
  __shared__ __attribute__((aligned(16))) u16 Vs[4][64 * 64];

  const int tid = threadIdx.x;
  const int lane = tid & 63, wave = tid >> 6;
  const int l31 = lane & 31, lh = lane >> 5;

  const int id = blockIdx.x;
  const int xcd = id & 7, sp = id >> 3;
  const int h = xcd * 2 + (sp & 1);
  const int qb = sp >> 1;
  const int q0 = qb * 128 + wave * 32;

  const u16* Qh = Q + (size_t)h * S_LEN * HDIM;
  const u16* Kh = Kg + (size_t)h * S_LEN * HDIM;
  const u16* Vh = Vt + (size_t)h * HDIM * S_LEN;

  v8s qf[4];
#pragma unroll
  for (int ks = 0; ks < 4; ++ks)
    qf[ks] = *reinterpret_cast<const v8s*>(
        Qh + (size_t)(q0 + l31) * HDIM + ks * 16 + lh * 8);

  const f32x16 z16 = vzero16();
  f32x16 oacc[2];
  oacc[0] = z16; oacc[1] = z16;
  float lsum = 0.f;

  const int s0i = tid, s1i = tid + 256;
  const int r0 = s0i >> 3, c0 = ((s0i & 7) ^ (r0 & 7)) * 8;
  const int r1 = s1i >> 3, c1 = ((s1i & 7) ^ (r1 & 7)) * 8;

  auto stageKV = [&](int b, int t) {
    const int kv0 = t * 64;
    gstage16(Kh + (size_t)(kv0 + r0) * HDIM + c0, &Ks[b][(wave * 64) * 8]);
    gstage16(Kh + (size_t)(kv0 + r1) * HDIM + c1, &Ks[b][(256 + wave * 64) * 8]);
    gstage16(Vh + (size_t)r0 * S_LEN + kv0 + c0, &Vs[b][(wave * 64) * 8]);
    gstage16(Vh + (size_t)r1 * S_LEN + kv0 + c1, &Vs[b][(256 + wave * 64) * 8]);
  };

  auto qk = [&](const u16* Kb, f32x16 (&sO)[2]) {
    __builtin_amdgcn_s_setprio(1);
#pragma unroll
    for (int j = 0; j < 2; ++j) {
      const int row = j * 32 + l31;
      v8s k0 = *reinterpret_cast<const v8s*>(
          Kb + (size_t)(row * 8 + ((0 + lh) ^ (row & 7))) * 8);
      sO[j] = __builtin_amdgcn_mfma_f32_32x32x16_bf16(k0, qf[0], z16, 0, 0, 0);
#pragma unroll
      for (int ks = 1; ks < 4; ++ks) {
        v8s kf = *reinterpret_cast<const v8s*>(
            Kb + (size_t)(row * 8 + ((ks * 2 + lh) ^ (row & 7))) * 8);
        sO[j] = __builtin_amdgcn_mfma_f32_32x32x16_bf16(kf, qf[ks], sO[j], 0, 0, 0);
      }
    }
    __builtin_amdgcn_s_setprio(0);
  };

  auto pack = [&](f32x16 (&sIn)[2], v8s (&pf)[4]) {
#pragma unroll
    for (int jj = 0; jj < 2; ++jj) {
      float p[16];
#pragma unroll
      for (int r = 0; r < 16; ++r) p[r] = fexp2(sIn[jj][r]);
      lsum += ((p[0] + p[1]) + (p[2] + p[3])) + ((p[4] + p[5]) + (p[6] + p[7])) +
              (((p[8] + p[9]) + (p[10] + p[11])) + ((p[12] + p[13]) + (p[14] + p[15])));
      u32 X1, X2, X3, X4, Y1, Y2, Y3, Y4;
      asm("v_cvt_pk_bf16_f32 %0, %1, %2" : "=v"(X1) : "v"(p[0]), "v"(p[1]));
      asm("v_cvt_pk_bf16_f32 %0, %1, %2" : "=v"(Y1) : "v"(p[4]), "v"(p[5]));
      asm("v_cvt_pk_bf16_f32 %0, %1, %2" : "=v"(X2) : "v"(p[2]), "v"(p[3]));
      asm("v_cvt_pk_bf16_f32 %0, %1, %2" : "=v"(Y2) : "v"(p[6]), "v"(p[7]));
      asm("v_cvt_pk_bf16_f32 %0, %1, %2" : "=v"(X3) : "v"(p[8]), "v"(p[9]));
      asm("v_cvt_pk_bf16_f32 %0, %1, %2" : "=v"(Y3) : "v"(p[12]), "v"(p[13]));
      asm("v_cvt_pk_bf16_f32 %0, %1, %2" : "=v"(X4) : "v"(p[10]), "v"(p[11]));
      asm("v_cvt_pk_bf16_f32 %0, %1, %2" : "=v"(Y4) : "v"(p[14]), "v"(p[15]));
      asm("v_permlane32_swap_b32 %0, %1" : "+v"(X1), "+v"(Y1));
      asm("v_permlane32_swap_b32 %0, %1" : "+v"(X2), "+v"(Y2));
      asm("v_permlane32_swap_b32 %0, %1" : "+v"(X3), "+v"(Y3));
      asm("v_permlane32_swap_b32 %0, %1" : "+v"(X4), "+v"(Y4));
      uint4 w0; w0.x = X1; w0.y = X2; w0.z = Y1; w0.w = Y2;
      uint4 w1; w1.x = X3; w1.y = X4; w1.z = Y3; w1.w = Y4;
      pf[jj * 2 + 0] = *reinterpret_cast<const v8s*>(&w0);
      pf[jj * 2 + 1] = *reinterpret_cast<const v8s*>(&w1);
    }
  };

  auto pv = [&](const u16* Vb, v8s (&pf)[4]) {
    v8s vf[2][4];
#pragma unroll
    for (int n = 0; n < 2; ++n) {
      const int row = n * 32 + l31;
#pragma unroll
      for (int ks = 0; ks < 4; ++ks)
        vf[n][ks] = *reinterpret_cast<const v8s*>(
            Vb + (size_t)(row * 8 + ((ks * 2 + lh) ^ (row & 7))) * 8);
    }
    __builtin_amdgcn_s_setprio(1);
#pragma unroll
    for (int ks = 0; ks < 4; ++ks) {
      oacc[0] = __builtin_amdgcn_mfma_f32_32x32x16_bf16(pf[ks], vf[0][ks], oacc[0], 0, 0, 0);
      oacc[1] = __builtin_amdgcn_mfma_f32_32x32x16_bf16(pf[ks], vf[1][ks], oacc[1], 0, 0, 0);
    }
    __builtin_amdgcn_s_setprio(0);
  };

  f32x16 sacc0[2], sacc1[2];

  auto body2 = [&](int t, int b0, int b1, int b2, int b3, bool doStage) {
    asm volatile("s_waitcnt vmcnt(0)\n\ts_barrier" ::: "memory");
    if (doStage) { stageKV(b2, t + 2); stageKV(b3, t + 3); }
    qk(&Ks[b0][0], sacc0);
    qk(&Ks[b1][0], sacc1);
    v8s pf0[4], pf1[4];
    pack(sacc0, pf0);
    pack(sacc1, pf1);
    pv(&Vs[b0][0], pf0);
    pv(&Vs[b1][0], pf1);
  };

  stageKV(0, 0);
  stageKV(1, 1);

  for (int tt = 0; tt < 60; tt += 4) {
    body2(tt, 0, 1, 2, 3, true);
    body2(tt + 2, 2, 3, 0, 1, true);
  }
  body2(60, 0, 1, 2, 3, true);
  body2(62, 2, 3, 0, 1, false);

  u32 ua = __float_as_uint(lsum), ub = ua;
  asm("v_permlane32_swap_b32 %0, %1" : "+v"(ua), "+v"(ub));
  const float lf = __uint_as_float(ua) + __uint_as_float(ub);

#pragma unroll
  for (int r = 0; r < 16; ++r) {
    const int crow = (r & 3) + 8 * (r >> 2) + 4 * lh;
    const float inv = __builtin_amdgcn_rcpf(__shfl(lf, crow));
    const int q = q0 + crow;
    const size_t base = (size_t)q * DM + h * HDIM + l31;
    Aout[base] = f2bs(oacc[0][r] * inv);
    Aout[base + 32] = f2bs(oacc[1][r] * inv);
  }
}

// ---- launcher ----------------------------------------------------------
extern "C" void kernel_launch(void* const* d_in, const int* in_sizes, int n_in,
                              void* d_out, int out_size, void* d_ws, size_t ws_size,
                              hipStream_t stream) {
  const float* x  = (const float*)d_in[0];
  const float* wq = (const float*)d_in[1];
  const float* bq = (const float*)d_in[2];
  const float* wk = (const float*)d_in[3];
  const float* bk = (const float*)d_in[4];
  const float* wv = (const float*)d_in[5];
  const float* bv = (const float*)d_in[6];
  const float* wo = (const float*)d_in[7];
  const float* bo = (const float*)d_in[8];
  float* out = (float*)d_out;

  char* ws = (char*)d_ws;
  u16* xb  = (u16*)(ws);                          // [4096][1024] bf16, 8MB
  u16* wqT = (u16*)(ws + (8u << 20));             // [1024][1024] bf16, 2MB each
  u16* wkT = wqT + 1024 * 1024;
  u16* wvT = wkT + 1024 * 1024;
  u16* woT = wvT + 1024 * 1024;
  u16* Qh  = (u16*)(ws + (16u << 20));            // [16][4096][64] bf16, 8MB
  u16* Kh  = Qh + 16 * 4096 * 64;
  u16* Vth = Kh + 16 * 4096 * 64;                 // [16][64][4096]
  u16* Ao  = Vth + 16 * 4096 * 64;                // [4096][1024]

  dim3 pg(16, 16, 5);
  k_prep<<<pg, 256, 0, stream>>>(x, wq, wk, wv, wo, xb, wqT, wkT, wvT, woT);
  dim3 gg(32, 8, 3);
  k_gemm_qkv<<<gg, 256, 0, stream>>>(xb, wqT, wkT, wvT, bq, bk, bv, Qh, Kh, Vth);
  k_attn<<<512, 256, 0, stream>>>(Qh, Kh, Vth, Ao);
  dim3 og(32, 16);
  k_gemm_o<<<og, 256, 0, stream>>>(Ao, woT, bo, out);
}